// Round 1
// baseline (403.862 us; speedup 1.0000x reference)
//
#include <hip/hip_runtime.h>

// Problem constants: B=8, Md=256, L=31, N2=Md+L-1=286, SHOTS=2, UP=2
#define NX    16252928u   // 8*256*256*31   (elements of X)
#define NPAIR 8126464u    // NX/2
#define NOUT  65011712u   // 8*512*512*31   (output elements)
#define NOUT4 16252928u   // NOUT/4

// Pass 1: X[e] = H2[e].x*Y2[y].x + H2[e].y*Y2[y].y ; global max via block atomicMax.
// H loaded as float4 (two consecutive X-elements' SHOTS pairs).
// STORE=false variant used only if workspace is too small for X.
template <bool STORE>
__global__ __launch_bounds__(256) void k_compute_x_max(
    const float4* __restrict__ H4, const float2* __restrict__ Y2,
    float2* __restrict__ X2, int* __restrict__ maxslot)
{
    float m = 0.0f;
    const unsigned stride = gridDim.x * blockDim.x;
    for (unsigned p = blockIdx.x * blockDim.x + threadIdx.x; p < NPAIR; p += stride) {
        unsigned e0 = 2u * p;
        unsigned e1 = e0 + 1u;
        // e = (bm*256 + i)*31 + l ; y2 index = bm*286 + i + l
        unsigned q0 = e0 / 31u, l0 = e0 - q0 * 31u;
        unsigned q1 = e1 / 31u, l1 = e1 - q1 * 31u;
        unsigned y0 = (q0 >> 8) * 286u + (q0 & 255u) + l0;
        unsigned y1 = (q1 >> 8) * 286u + (q1 & 255u) + l1;
        float4 h  = H4[p];
        float2 ya = Y2[y0];
        float2 yb = Y2[y1];
        float x0 = h.x * ya.x + h.y * ya.y;
        float x1 = h.z * yb.x + h.w * yb.y;
        if (STORE) X2[p] = make_float2(x0, x1);
        m = fmaxf(m, fmaxf(x0, x1));
    }
    // wave(64) butterfly reduce
    #pragma unroll
    for (int off = 32; off > 0; off >>= 1)
        m = fmaxf(m, __shfl_xor(m, off, 64));
    __shared__ float wmax[4];
    const int lane = threadIdx.x & 63, wid = threadIdx.x >> 6;
    if (lane == 0) wmax[wid] = m;
    __syncthreads();
    if (threadIdx.x == 0) {
        float bm = fmaxf(fmaxf(wmax[0], wmax[1]), fmaxf(wmax[2], wmax[3]));
        // all X >= 0 -> int compare on float bits is order-preserving.
        // ws poison 0xAAAAAAAA is a negative int => acts as -inf seed.
        atomicMax(maxslot, __float_as_int(bm));
    }
}

// Pass 2 (main path): out[b,p,q,l] = X[b,p/2,q/2,l] * inv_max, float4 stores.
__global__ __launch_bounds__(256) void k_upsample(
    const float* __restrict__ X, const int* __restrict__ maxslot,
    float4* __restrict__ out)
{
    const float inv = 1.0f / __int_as_float(*maxslot);
    const unsigned stride = gridDim.x * blockDim.x;
    for (unsigned g = blockIdx.x * blockDim.x + threadIdx.x; g < NOUT4; g += stride) {
        const unsigned t = 4u * g;
        float4 v;
        float* vp = &v.x;
        #pragma unroll
        for (int j = 0; j < 4; ++j) {
            unsigned e = t + (unsigned)j;
            unsigned r = e / 31u, l = e - r * 31u;
            unsigned q  = r & 511u;
            unsigned pp = (r >> 9) & 511u;
            unsigned b  = r >> 18;
            unsigned xi = ((((b << 8) + (pp >> 1)) << 8) | (q >> 1)) * 31u + l;
            vp[j] = X[xi] * inv;
        }
        out[g] = v;
    }
}

// Pass 2 (fallback, ws too small): recompute X from H,Y per output element.
__global__ __launch_bounds__(256) void k_upsample_recompute(
    const float2* __restrict__ H2, const float2* __restrict__ Y2,
    const int* __restrict__ maxslot, float4* __restrict__ out)
{
    const float inv = 1.0f / __int_as_float(*maxslot);
    const unsigned stride = gridDim.x * blockDim.x;
    for (unsigned g = blockIdx.x * blockDim.x + threadIdx.x; g < NOUT4; g += stride) {
        const unsigned t = 4u * g;
        float4 v;
        float* vp = &v.x;
        #pragma unroll
        for (int j = 0; j < 4; ++j) {
            unsigned e = t + (unsigned)j;
            unsigned r = e / 31u, l = e - r * 31u;
            unsigned q  = r & 511u;
            unsigned pp = (r >> 9) & 511u;
            unsigned b  = r >> 18;
            unsigned m  = pp >> 1, i = q >> 1;
            unsigned bm = (b << 8) + m;
            unsigned hidx = ((bm << 8) + i) * 31u + l;
            unsigned yidx = bm * 286u + i + l;
            float2 h = H2[hidx];
            float2 y = Y2[yidx];
            vp[j] = (h.x * y.x + h.y * y.y) * inv;
        }
        out[g] = v;
    }
}

extern "C" void kernel_launch(void* const* d_in, const int* in_sizes, int n_in,
                              void* d_out, int out_size, void* d_ws, size_t ws_size,
                              hipStream_t stream) {
    const float* Y = (const float*)d_in[0];   // (8,256,286,2)
    const float* H = (const float*)d_in[1];   // (8,256,256,31,2)

    int*    maxslot = (int*)d_ws;                       // 4 B (poisoned negative = -inf)
    float2* X2      = (float2*)((char*)d_ws + 256);     // 65 MB X buffer
    const size_t need = 256 + (size_t)NX * 4;

    const float4* H4 = (const float4*)H;
    const float2* Y2 = (const float2*)Y;
    float4* out4 = (float4*)d_out;

    if (ws_size >= need) {
        k_compute_x_max<true><<<1024, 256, 0, stream>>>(H4, Y2, X2, maxslot);
        k_upsample<<<4096, 256, 0, stream>>>((const float*)X2, maxslot, out4);
    } else {
        k_compute_x_max<false><<<1024, 256, 0, stream>>>(H4, Y2, nullptr, maxslot);
        k_upsample_recompute<<<4096, 256, 0, stream>>>((const float2*)H, Y2, maxslot, out4);
    }
}

// Round 2
// 384.847 us; speedup vs baseline: 1.0494x; 1.0494x over previous
//
#include <hip/hip_runtime.h>

// B=8, Md=256, L=31, N2=286, SHOTS=2, UP=2
// X[b,m,i,l] = sum_s H[b,m,i,l,s] * Y[b,m,i+l,s]   (no wrap: i+l <= 285 < 286)
// out[b,p,q,l] = X[b,p/2,q/2,l] / max(X)
#define NPAIR 8126464u    // H float4 count = 8*256*256*31*2/4

// Pass 1: global max of X. Pure streaming read of H.
__global__ __launch_bounds__(256) void k_max(
    const float4* __restrict__ H4, const float2* __restrict__ Y2,
    int* __restrict__ maxslot)
{
    float m = 0.0f;
    const unsigned stride = gridDim.x * blockDim.x;
    for (unsigned p = blockIdx.x * blockDim.x + threadIdx.x; p < NPAIR; p += stride) {
        unsigned e0 = 2u * p, e1 = e0 + 1u;
        unsigned q0 = e0 / 31u, l0 = e0 - q0 * 31u;
        unsigned q1 = e1 / 31u, l1 = e1 - q1 * 31u;
        unsigned y0 = (q0 >> 8) * 286u + (q0 & 255u) + l0;
        unsigned y1 = (q1 >> 8) * 286u + (q1 & 255u) + l1;
        float4 h = H4[p];
        float2 ya = Y2[y0], yb = Y2[y1];
        m = fmaxf(m, fmaxf(h.x * ya.x + h.y * ya.y, h.z * yb.x + h.w * yb.y));
    }
    #pragma unroll
    for (int off = 32; off > 0; off >>= 1)
        m = fmaxf(m, __shfl_xor(m, off, 64));
    __shared__ float wmax[4];
    const int lane = threadIdx.x & 63, wid = threadIdx.x >> 6;
    if (lane == 0) wmax[wid] = m;
    __syncthreads();
    if (threadIdx.x == 0) {
        float bmax = fmaxf(fmaxf(wmax[0], wmax[1]), fmaxf(wmax[2], wmax[3]));
        // X >= 0 so int-compare on float bits is order-preserving;
        // ws poison 0xAAAAAAAA is negative => acts as -inf seed.
        atomicMax(maxslot, __float_as_int(bmax));
    }
}

// Pass 2: recompute X for 32 chunks (b,m, i0..i0+31) into LDS, then write the
// 2x2-upsampled, normalized output with fully coalesced float4 stores.
// blockIdx.x = bm*8 + ti ; i0 = 32*ti. LDS holds 32*31 = 992 X floats.
__global__ __launch_bounds__(256) void k_out(
    const float4* __restrict__ H4, const float2* __restrict__ Y2,
    const int* __restrict__ maxslot, float4* __restrict__ out4)
{
    __shared__ float xs[992];
    const unsigned bm = blockIdx.x >> 3;
    const unsigned ti = blockIdx.x & 7u;
    const float inv = 1.0f / __int_as_float(*maxslot);

    // ---- compute phase: 496 H float4 loads -> 992 X values in LDS ----
    const unsigned h4base = bm * 3968u + ti * 496u;  // (bm*256 + ti*32)*31*2 /4
    const unsigned ybase  = bm * 286u + ti * 32u;    // + c + l gives Y2 index
    for (unsigned f2 = threadIdx.x; f2 < 496u; f2 += 256u) {
        unsigned f  = 2u * f2;
        unsigned c0 = f / 31u,        l0 = f        - c0 * 31u;
        unsigned c1 = (f + 1u) / 31u, l1 = (f + 1u) - c1 * 31u;
        float4 h  = H4[h4base + f2];
        float2 ya = Y2[ybase + c0 + l0];
        float2 yb = Y2[ybase + c1 + l1];
        xs[f]      = h.x * ya.x + h.y * ya.y;
        xs[f + 1u] = h.z * yb.x + h.w * yb.y;
    }
    __syncthreads();

    // ---- write phase: rows p=2m and 2m+1, q in [64*ti, 64*ti+64), 31 l's ----
    // segment = 64 out-chunks * 31 floats = 1984 floats = 496 float4 per row
    const unsigned b = bm >> 8, mrow = bm & 255u;
    float4* r0 = out4 + (size_t)((b * 512u + 2u * mrow) * 3968u + ti * 496u);
    float4* r1 = r0 + 3968u;   // next output row (identical data)
    for (unsigned g = threadIdx.x; g < 496u; g += 256u) {
        float4 v;
        float* vp = &v.x;
        #pragma unroll
        for (int k = 0; k < 4; ++k) {
            unsigned s  = 4u * g + (unsigned)k;
            unsigned oc = s / 31u, r = s - oc * 31u;
            vp[k] = xs[(oc >> 1) * 31u + r] * inv;
        }
        r0[g] = v;
        r1[g] = v;
    }
}

extern "C" void kernel_launch(void* const* d_in, const int* in_sizes, int n_in,
                              void* d_out, int out_size, void* d_ws, size_t ws_size,
                              hipStream_t stream) {
    const float* Y = (const float*)d_in[0];   // (8,256,286,2)
    const float* H = (const float*)d_in[1];   // (8,256,256,31,2)

    int* maxslot = (int*)d_ws;  // poisoned 0xAAAAAAAA (negative) = -inf seed

    k_max<<<2048, 256, 0, stream>>>((const float4*)H, (const float2*)Y, maxslot);
    k_out<<<8 * 256 * 8, 256, 0, stream>>>((const float4*)H, (const float2*)Y,
                                           maxslot, (float4*)d_out);
}

// Round 5
// 373.943 us; speedup vs baseline: 1.0800x; 1.0292x over previous
//
#include <hip/hip_runtime.h>

// B=8, Md=256, L=31, N2=286, SHOTS=2, UP=2
// X[b,m,i,l] = sum_s H[b,m,i,l,s] * Y[b,m,i+l,s]   (no wrap: i+l <= 285 < 286)
// out[b,p,q,l] = X[b,p/2,q/2,l] / max(X)
#define NPAIR 8126464u    // H float4 count = 8*256*256*31*2/4

// native clang vector type — required by __builtin_nontemporal_store
typedef float vfloat4 __attribute__((ext_vector_type(4)));

// Pass 1: global max of X. Pure streaming read of H (fills L3 for pass 2).
__global__ __launch_bounds__(256) void k_max(
    const float4* __restrict__ H4, const float2* __restrict__ Y2,
    int* __restrict__ maxslot)
{
    float m = 0.0f;
    const unsigned stride = gridDim.x * blockDim.x;
    for (unsigned p = blockIdx.x * blockDim.x + threadIdx.x; p < NPAIR; p += stride) {
        unsigned e0 = 2u * p, e1 = e0 + 1u;
        unsigned q0 = e0 / 31u, l0 = e0 - q0 * 31u;
        unsigned q1 = e1 / 31u, l1 = e1 - q1 * 31u;
        unsigned y0 = (q0 >> 8) * 286u + (q0 & 255u) + l0;
        unsigned y1 = (q1 >> 8) * 286u + (q1 & 255u) + l1;
        float4 h = H4[p];
        float2 ya = Y2[y0], yb = Y2[y1];
        m = fmaxf(m, fmaxf(h.x * ya.x + h.y * ya.y, h.z * yb.x + h.w * yb.y));
    }
    #pragma unroll
    for (int off = 32; off > 0; off >>= 1)
        m = fmaxf(m, __shfl_xor(m, off, 64));
    __shared__ float wmax[4];
    const int lane = threadIdx.x & 63, wid = threadIdx.x >> 6;
    if (lane == 0) wmax[wid] = m;
    __syncthreads();
    if (threadIdx.x == 0) {
        float bmax = fmaxf(fmaxf(wmax[0], wmax[1]), fmaxf(wmax[2], wmax[3]));
        // X >= 0 so int-compare on float bits is order-preserving;
        // ws poison 0xAAAAAAAA is negative => acts as -inf seed.
        atomicMax(maxslot, __float_as_int(bmax));
    }
}

// Pass 2: recompute X for a chunk (bm, i0..i0+31) into LDS (H read hits L3),
// then write the 2x2-upsampled, normalized output with coalesced nontemporal
// float4 stores (out is write-once: bypass caches, keep H resident in L3).
__global__ __launch_bounds__(256) void k_out(
    const float4* __restrict__ H4, const float2* __restrict__ Y2,
    const int* __restrict__ maxslot, vfloat4* __restrict__ out4)
{
    __shared__ float xs[992];
    const unsigned bm = blockIdx.x >> 3;
    const unsigned ti = blockIdx.x & 7u;
    const float inv = 1.0f / __int_as_float(*maxslot);

    // ---- compute phase: 496 H float4 loads -> 992 X values in LDS ----
    const unsigned h4base = bm * 3968u + ti * 496u;  // (bm*256 + ti*32)*31*2 /4
    const unsigned ybase  = bm * 286u + ti * 32u;    // + c + l gives Y2 index
    for (unsigned f2 = threadIdx.x; f2 < 496u; f2 += 256u) {
        unsigned f  = 2u * f2;
        unsigned c0 = f / 31u,        l0 = f        - c0 * 31u;
        unsigned c1 = (f + 1u) / 31u, l1 = (f + 1u) - c1 * 31u;
        float4 h  = H4[h4base + f2];
        float2 ya = Y2[ybase + c0 + l0];
        float2 yb = Y2[ybase + c1 + l1];
        xs[f]      = h.x * ya.x + h.y * ya.y;
        xs[f + 1u] = h.z * yb.x + h.w * yb.y;
    }
    __syncthreads();

    // ---- write phase: rows p=2m,2m+1; q in [64*ti, 64*ti+64); 31 l's ----
    // segment = 64 out-chunks * 31 floats = 1984 floats = 496 float4 per row
    const unsigned b = bm >> 8, mrow = bm & 255u;
    vfloat4* r0 = out4 + (size_t)((b * 512u + 2u * mrow) * 3968u + ti * 496u);
    vfloat4* r1 = r0 + 3968u;   // next output row (identical data)
    for (unsigned g = threadIdx.x; g < 496u; g += 256u) {
        vfloat4 v;
        #pragma unroll
        for (int k = 0; k < 4; ++k) {
            unsigned s  = 4u * g + (unsigned)k;
            unsigned oc = s / 31u, r = s - oc * 31u;
            v[k] = xs[(oc >> 1) * 31u + r] * inv;
        }
        __builtin_nontemporal_store(v, &r0[g]);
        __builtin_nontemporal_store(v, &r1[g]);
    }
}

extern "C" void kernel_launch(void* const* d_in, const int* in_sizes, int n_in,
                              void* d_out, int out_size, void* d_ws, size_t ws_size,
                              hipStream_t stream) {
    const float* Y = (const float*)d_in[0];   // (8,256,286,2)
    const float* H = (const float*)d_in[1];   // (8,256,256,31,2)

    int* maxslot = (int*)d_ws;  // poisoned 0xAAAAAAAA (negative) = -inf seed

    k_max<<<2048, 256, 0, stream>>>((const float4*)H, (const float2*)Y, maxslot);
    k_out<<<8 * 256 * 8, 256, 0, stream>>>((const float4*)H, (const float2*)Y,
                                           maxslot, (vfloat4*)d_out);
}